// Round 7
// baseline (23838.081 us; speedup 1.0000x reference)
//
#include <hip/hip_runtime.h>
#include <hip/hip_fp16.h>
#include <cstdint>
#include <cmath>

typedef _Float16 f16x8 __attribute__((ext_vector_type(8)));
typedef float f32x4 __attribute__((ext_vector_type(4)));

#define MFMA16(A, B, C) __builtin_amdgcn_mfma_f32_16x16x32_f16(A, B, C, 0, 0, 0)
#define LO_SCALE 2048.0f
#define LO_INV   4.8828125e-4f

// ---------------- fp32 tiled GEMM (kept only for the tiny wcomb GEMMs) ------------
#define GBM 128
#define GBN 128
#define GBK 16

template<bool TRANSB>
__global__ __launch_bounds__(256)
void gemm_f32(int M, int N, int K,
              const float* __restrict__ A, long long sA,
              const float* __restrict__ B, long long sB,
              float* __restrict__ Cc, long long sC,
              const float* __restrict__ bias,
              const float* __restrict__ rsA,
              const float* __restrict__ rsB)
{
    const int z = blockIdx.z;
    A  += (size_t)z * (size_t)sA;
    B  += (size_t)z * (size_t)sB;
    Cc += (size_t)z * (size_t)sC;

    const int bm = blockIdx.y * GBM;
    const int bn = blockIdx.x * GBN;
    const int tid = threadIdx.x;
    const int tx = tid & 15;
    const int ty = tid >> 4;

    __shared__ float As[GBK][GBM + 4];
    __shared__ float Bs[GBK][GBN + 4];

    float acc[8][8];
#pragma unroll
    for (int i = 0; i < 8; ++i)
#pragma unroll
        for (int j = 0; j < 8; ++j) acc[i][j] = 0.0f;

    const int lr = tid >> 2;
    const int lk = (tid & 3) << 2;
    const int kb_n = tid >> 5;
    const int nb_n = (tid & 31) << 2;

    float sa0 = 1.f, sa1 = 1.f, sb0 = 1.f, sb1 = 1.f;
    if (rsA) {
        sa0 = rsA[(size_t)z * M + bm + lr];
        sa1 = rsA[(size_t)z * M + bm + lr + 64];
    }
    if (TRANSB && rsB) {
        sb0 = rsB[(size_t)z * N + bn + lr];
        sb1 = rsB[(size_t)z * N + bn + lr + 64];
    }

    float4 pa0, pa1, pb0, pb1;

    auto gload = [&](int kt) {
        const float* pA = A + (size_t)(bm + lr) * K + kt * GBK + lk;
        pa0 = *(const float4*)pA;
        pa1 = *(const float4*)(pA + (size_t)64 * K);
        if (TRANSB) {
            const float* pB = B + (size_t)(bn + lr) * K + kt * GBK + lk;
            pb0 = *(const float4*)pB;
            pb1 = *(const float4*)(pB + (size_t)64 * K);
        } else {
            const float* pB = B + (size_t)(kt * GBK + kb_n) * N + bn + nb_n;
            pb0 = *(const float4*)pB;
            pb1 = *(const float4*)(pB + (size_t)8 * N);
        }
    };
    auto sstore = [&]() {
        As[lk + 0][lr] = pa0.x * sa0; As[lk + 1][lr] = pa0.y * sa0;
        As[lk + 2][lr] = pa0.z * sa0; As[lk + 3][lr] = pa0.w * sa0;
        As[lk + 0][lr + 64] = pa1.x * sa1; As[lk + 1][lr + 64] = pa1.y * sa1;
        As[lk + 2][lr + 64] = pa1.z * sa1; As[lk + 3][lr + 64] = pa1.w * sa1;
        if (TRANSB) {
            Bs[lk + 0][lr] = pb0.x * sb0; Bs[lk + 1][lr] = pb0.y * sb0;
            Bs[lk + 2][lr] = pb0.z * sb0; Bs[lk + 3][lr] = pb0.w * sb0;
            Bs[lk + 0][lr + 64] = pb1.x * sb1; Bs[lk + 1][lr + 64] = pb1.y * sb1;
            Bs[lk + 2][lr + 64] = pb1.z * sb1; Bs[lk + 3][lr + 64] = pb1.w * sb1;
        } else {
            *(float4*)&Bs[kb_n][nb_n]     = pb0;
            *(float4*)&Bs[kb_n + 8][nb_n] = pb1;
        }
    };

    const int nkt = K / GBK;
    gload(0);
    sstore();
    __syncthreads();
    for (int kt = 0; kt < nkt; ++kt) {
        if (kt + 1 < nkt) gload(kt + 1);
#pragma unroll
        for (int k = 0; k < GBK; ++k) {
            float4 a0 = *(const float4*)&As[k][ty * 8];
            float4 a1 = *(const float4*)&As[k][ty * 8 + 4];
            float4 b0 = *(const float4*)&Bs[k][tx * 8];
            float4 b1 = *(const float4*)&Bs[k][tx * 8 + 4];
            float av[8] = {a0.x, a0.y, a0.z, a0.w, a1.x, a1.y, a1.z, a1.w};
            float bv[8] = {b0.x, b0.y, b0.z, b0.w, b1.x, b1.y, b1.z, b1.w};
#pragma unroll
            for (int i = 0; i < 8; ++i)
#pragma unroll
                for (int j = 0; j < 8; ++j)
                    acc[i][j] = fmaf(av[i], bv[j], acc[i][j]);
        }
        __syncthreads();
        if (kt + 1 < nkt) { sstore(); __syncthreads(); }
    }

    float bb[8];
#pragma unroll
    for (int j = 0; j < 8; ++j) bb[j] = bias ? bias[bn + tx * 8 + j] : 0.0f;
#pragma unroll
    for (int i = 0; i < 8; ++i) {
        const int row = bm + ty * 8 + i;
        float* cp = Cc + (size_t)row * N + bn + tx * 8;
        float4 o0 = make_float4(acc[i][0] + bb[0], acc[i][1] + bb[1],
                                acc[i][2] + bb[2], acc[i][3] + bb[3]);
        float4 o1 = make_float4(acc[i][4] + bb[4], acc[i][5] + bb[5],
                                acc[i][6] + bb[6], acc[i][7] + bb[7]);
        *(float4*)cp = o0;
        *(float4*)(cp + 4) = o1;
    }
}

// ---------------- combined GRU input bias: bcomb = bih + Wih @ b_proj --------------
__global__ void bias_combine(const float* __restrict__ Wih, const float* __restrict__ b_proj,
                             const float* __restrict__ bih, float* __restrict__ bcomb)
{
    const int j = blockIdx.x * blockDim.x + threadIdx.x;
    if (j >= 768) return;
    float s = bih[j];
    for (int k = 0; k < 512; ++k) s = fmaf(Wih[(size_t)j * 512 + k], b_proj[k], s);
    bcomb[j] = s;
}

// ---------------- pack W[N=768][K=256] into MFMA fp16-split B-fragments ------------
// [nt 0..47][kc 0..7][plane 0..1][lane 0..63][j 0..7] u16.
__global__ __launch_bounds__(256)
void pack_w(const float* __restrict__ W, unsigned short* __restrict__ pack)
{
    const int idx = blockIdx.x * 256 + threadIdx.x;
    if (idx >= 768 * 256) return;
    const int n = idx >> 8;
    const int k = idx & 255;
    const float w = W[idx];
    const __half hi = __float2half(w);
    const __half lo = __float2half((w - __half2float(hi)) * LO_SCALE);
    const int nt = n >> 4;
    const int lane = ((k >> 3) & 3) * 16 + (n & 15);
    const int j = k & 7;
    const int kc = k >> 5;
    const size_t base = ((size_t)(nt * 8 + kc) * 2) * 512 + lane * 8 + j;
    pack[base]       = __half_as_ushort(hi);
    pack[base + 512] = __half_as_ushort(lo);
}

// ---------------- pack W[K][N] (row-major) into MFMA fp16-split fragments ----------
__global__ __launch_bounds__(256)
void pack_bk(const float* __restrict__ W, unsigned short* __restrict__ pack,
             int K, int N)
{
    const int idx = blockIdx.x * 256 + threadIdx.x;
    if (idx >= K * N) return;
    const int k = idx / N;
    const int n = idx - k * N;
    const float w = W[idx];
    const __half hi = __float2half(w);
    const __half lo = __float2half((w - __half2float(hi)) * LO_SCALE);
    const int nt = n >> 4;
    const int kc = k >> 5;
    const int lane = ((k >> 3) & 3) * 16 + (n & 15);
    const int j = k & 7;
    const int KC = K >> 5;
    const size_t base = ((size_t)(nt * KC + kc) * 2) * 512 + lane * 8 + j;
    pack[base]       = __half_as_ushort(hi);
    pack[base + 512] = __half_as_ushort(lo);
}

// ---------------- gi GEMM (MFMA fp16-split): gi = C @ wcomb^T + bcomb --------------
__global__ __launch_bounds__(512)
void gi_gemm(const float* __restrict__ Cm, const unsigned short* __restrict__ pack,
             const float* __restrict__ bcomb, float* __restrict__ gi)
{
    const int tid = threadIdx.x;
    const int w = tid >> 6, l = tid & 63;
    const int l15 = l & 15, l4 = l >> 4;
    const int m0 = blockIdx.x * 64;

    __shared__ unsigned short alds[2][64 * 256];

    {   // stage A tile: fp32 -> fp16 hi/lo planes with XOR swizzle
        const int row = tid >> 3;
        const int seg = (tid & 7) * 32;
        const float4* src = (const float4*)(Cm + (size_t)(m0 + row) * 256 + seg);
        const int sw = (row & 7) << 3;
#pragma unroll
        for (int i = 0; i < 8; ++i) {
            float4 v = src[i];
            float vv[4] = {v.x, v.y, v.z, v.w};
#pragma unroll
            for (int e = 0; e < 4; ++e) {
                const float x = vv[e];
                const __half hi = __float2half(x);
                const __half lo = __float2half((x - __half2float(hi)) * LO_SCALE);
                const int ad = (row << 8) + ((seg + i * 4 + e) ^ sw);
                alds[0][ad] = __half_as_ushort(hi);
                alds[1][ad] = __half_as_ushort(lo);
            }
        }
    }
    __syncthreads();

    const int mt = w >> 1, nh = w & 1;
    f32x4 acc[24];
#pragma unroll
    for (int i = 0; i < 24; ++i) acc[i] = (f32x4){0.f, 0.f, 0.f, 0.f};

    const int ar = mt * 16 + l15;
    const int arow = ar << 8;
    const int asw = (ar & 7) << 3;

#pragma unroll
    for (int kc = 0; kc < 8; ++kc) {
        const int ad = arow + ((kc * 32 + l4 * 8) ^ asw);
        const f16x8 ahi = *(const f16x8*)&alds[0][ad];
        const f16x8 alo = *(const f16x8*)&alds[1][ad];
#pragma unroll
        for (int nt = 0; nt < 24; ++nt) {
            const int nt_lin = nh * 24 + nt;
            const uint4* bp = (const uint4*)(pack + ((size_t)(nt_lin * 8 + kc) * 2) * 512);
            uint4 bh4 = bp[l];
            uint4 bl4 = bp[64 + l];
            const f16x8 Bhi = *reinterpret_cast<const f16x8*>(&bh4);
            const f16x8 Blo = *reinterpret_cast<const f16x8*>(&bl4);
            acc[nt] = MFMA16(ahi, Bhi, acc[nt]);
            f32x4 t2 = (f32x4){0.f, 0.f, 0.f, 0.f};
            t2 = MFMA16(ahi, Blo, t2);
            t2 = MFMA16(alo, Bhi, t2);
#pragma unroll
            for (int r = 0; r < 4; ++r) acc[nt][r] = fmaf(LO_INV, t2[r], acc[nt][r]);
        }
    }

#pragma unroll
    for (int nt = 0; nt < 24; ++nt) {
        const int n = (nh * 24 + nt) * 16 + l15;
        const float bb = bcomb[n];
#pragma unroll
        for (int r = 0; r < 4; ++r) {
            const int m = m0 + mt * 16 + l4 * 4 + r;
            __builtin_nontemporal_store(acc[nt][r] + bb, &gi[(size_t)m * 768 + n]);
        }
    }
}

// ---------------- GRU scan v7: LDS-resident weights, cross-block h exchange --------
// 256 blocks (1/CU), 512 threads. 32 groups x 8 blocks; group g = (bid&7)*4 + ((bid>>3)>>3)
// so members share bid%8 (same-XCD heuristic; agent-scope atomics keep it correct
// regardless). Block c = (bid>>3)&7 owns units [c*32, c*32+32): weight fragments
// (6 nt-tiles x 8 kc x hi/lo = 96 KB) live in LDS for the whole scan. Per step:
// spin-barrier on group counter -> read peers' h (8KB) -> build A-frags (fp16 split)
// -> 24x3 MFMA on 6 waves -> activation on 256 threads -> write h slice + H + fence
// -> release-add. M=8 batches per group. Guarded spin (bounded) to avoid hangs.
__global__ __launch_bounds__(512)
void gru_scan_v7(const float* __restrict__ gi,
                 const unsigned short* __restrict__ pack,
                 const float* __restrict__ bhh,
                 float* __restrict__ H,
                 float* __restrict__ hx,          // [32][2][8][256] f32
                 unsigned int* __restrict__ cnt,  // [32]
                 int dir)
{
    const int bid = blockIdx.x;
    const int x = bid & 7;
    const int r = bid >> 3;       // 0..31
    const int c = r & 7;          // member -> units [c*32, c*32+32)
    const int s = r >> 3;         // 0..3
    const int g = x * 4 + s;      // group 0..31
    const int b0 = g * 8;

    const int tid = threadIdx.x;
    const int w = tid >> 6, l = tid & 63;
    const int l15 = l & 15, l4 = l >> 4;

    __shared__ unsigned short wlds[6][8][2][512];  // 96 KB
    __shared__ unsigned short afr[8][2][512];      // 16 KB
    __shared__ float gx[6][8][16];                 // 3 KB

    {   // load this block's 6 weight nt-tiles (once)
        const int ntg0 = 2 * c;
#pragma unroll
        for (int slot = 0; slot < 6; ++slot) {
            const int ntg = (slot < 2) ? (ntg0 + slot)
                          : (slot < 4) ? (16 + ntg0 + (slot - 2))
                                       : (32 + ntg0 + (slot - 4));
            const uint4* src = (const uint4*)(pack + ((size_t)ntg * 8 * 2) * 512);
            uint4* dst = (uint4*)&wlds[slot][0][0][0];
            for (int i = tid; i < 1024; i += 512) dst[i] = src[i];
        }
    }

    float bh_r = 0.f, bh_z = 0.f, bh_n = 0.f, hprev = 0.f;
    int u_loc = 0, m_act = 0;
    if (tid < 256) {
        u_loc = tid & 31;
        m_act = tid >> 5;
        const int u = c * 32 + u_loc;
        bh_r = bhh[u]; bh_z = bhh[u + 256]; bh_n = bhh[u + 512];
    }
    float* hx0 = hx + (size_t)g * 2 * 8 * 256;
    float* hx1 = hx0 + 8 * 256;
    unsigned int* mycnt = cnt + g;
    __syncthreads();

    for (int t = 0; t < 256; ++t) {
        const int tt = dir ? (255 - t) : t;

        // gi prefetch (independent of the barrier)
        float g_r = 0.f, g_z = 0.f, g_n = 0.f;
        if (tid < 256) {
            const float* gp = gi + ((size_t)(b0 + m_act) * 256 + tt) * 768 + c * 32 + u_loc;
            g_r = __builtin_nontemporal_load(gp);
            g_z = __builtin_nontemporal_load(gp + 256);
            g_n = __builtin_nontemporal_load(gp + 512);
        }

        if (t > 0) {
            if (tid == 0) {
                const unsigned int target = (unsigned int)(8 * t);
                int guard = 0;
                while (__hip_atomic_load(mycnt, __ATOMIC_ACQUIRE,
                                         __HIP_MEMORY_SCOPE_AGENT) < target) {
                    if (++guard > (1 << 22)) break;
                }
            }
            __syncthreads();
        }

        {   // build A-fragments from h[t-1] (zeros at t==0 / batches >= 8)
            const float* hsrc = (t & 1) ? hx0 : hx1;   // (t-1)&1
            const int kc = tid >> 6;
            float v[8];
            if (l15 < 8 && t > 0) {
                const float* hp = hsrc + (size_t)l15 * 256 + kc * 32 + l4 * 8;
                float4 a = *(const float4*)hp;
                float4 b2 = *(const float4*)(hp + 4);
                v[0] = a.x; v[1] = a.y; v[2] = a.z; v[3] = a.w;
                v[4] = b2.x; v[5] = b2.y; v[6] = b2.z; v[7] = b2.w;
            } else {
#pragma unroll
                for (int j = 0; j < 8; ++j) v[j] = 0.f;
            }
            unsigned short hi8[8], lo8[8];
#pragma unroll
            for (int j = 0; j < 8; ++j) {
                const __half h1 = __float2half(v[j]);
                const __half l1 = __float2half((v[j] - __half2float(h1)) * LO_SCALE);
                hi8[j] = __half_as_ushort(h1);
                lo8[j] = __half_as_ushort(l1);
            }
            *(uint4*)&afr[kc][0][l * 8] = *(uint4*)hi8;
            *(uint4*)&afr[kc][1][l * 8] = *(uint4*)lo8;
        }
        __syncthreads();

        if (w < 6) {   // MFMA phase: wave w owns nt-slot w
            f32x4 a1 = (f32x4){0.f, 0.f, 0.f, 0.f};
            f32x4 a2 = (f32x4){0.f, 0.f, 0.f, 0.f};
#pragma unroll
            for (int kc = 0; kc < 8; ++kc) {
                const f16x8 ah = *(const f16x8*)&afr[kc][0][l * 8];
                const f16x8 al = *(const f16x8*)&afr[kc][1][l * 8];
                const f16x8 bh = *(const f16x8*)&wlds[w][kc][0][l * 8];
                const f16x8 bl = *(const f16x8*)&wlds[w][kc][1][l * 8];
                a1 = MFMA16(ah, bh, a1);
                a2 = MFMA16(ah, bl, a2);
                a2 = MFMA16(al, bh, a2);
            }
            if (l4 < 2) {
#pragma unroll
                for (int ri = 0; ri < 4; ++ri)
                    gx[w][l4 * 4 + ri][l15] = a1[ri] + LO_INV * a2[ri];
            }
        }
        __syncthreads();

        if (tid < 256) {   // activation + h/H writes
            const int sl = u_loc >> 4, ul = u_loc & 15;
            const float pr = gx[0 + sl][m_act][ul];
            const float pz = gx[2 + sl][m_act][ul];
            const float pn = gx[4 + sl][m_act][ul];
            const float rr = 1.0f / (1.0f + expf(-(g_r + pr + bh_r)));
            const float zz = 1.0f / (1.0f + expf(-(g_z + pz + bh_z)));
            const float nn = tanhf(g_n + rr * (pn + bh_n));
            hprev = (1.0f - zz) * nn + zz * hprev;
            float* hw = ((t & 1) ? hx1 : hx0) + (size_t)m_act * 256 + c * 32 + u_loc;
            *hw = hprev;
            __builtin_nontemporal_store(
                hprev,
                &H[((size_t)(b0 + m_act) * 256 + tt) * 512 + dir * 256 + c * 32 + u_loc]);
        }
        __threadfence();
        __syncthreads();
        if (tid == 0)
            __hip_atomic_fetch_add(mycnt, 1u, __ATOMIC_RELEASE, __HIP_MEMORY_SCOPE_AGENT);
    }
}

// ---------------- row 1/max(norm,1e-12) for cosine normalization ------------------
__global__ __launch_bounds__(256)
void rownorm(const float* __restrict__ H, float* __restrict__ rinv)
{
    const int row  = blockIdx.x * 4 + (threadIdx.x >> 6);
    const int lane = threadIdx.x & 63;
    const float4* p = (const float4*)(H + (size_t)row * 512);
    float ss = 0.f;
    float4 v = p[lane];
    ss += v.x * v.x + v.y * v.y + v.z * v.z + v.w * v.w;
    v = p[lane + 64];
    ss += v.x * v.x + v.y * v.y + v.z * v.z + v.w * v.w;
#pragma unroll
    for (int off = 32; off >= 1; off >>= 1) ss += __shfl_xor(ss, off);
    if (lane == 0) rinv[row] = 1.0f / fmaxf(sqrtf(ss), 1e-12f);
}

// ---------------- sim (MFMA fp16-split, batched 256x256x512, rinv folded) ----------
__global__ __launch_bounds__(512)
void sim_mfma(const float* __restrict__ H, const float* __restrict__ rinv,
              float* __restrict__ sim)
{
    const int b = blockIdx.x;
    const int tid = threadIdx.x;
    const int w = tid >> 6, l = tid & 63;
    const int l15 = l & 15, l4 = l >> 4;

    __shared__ unsigned short st[2][256][40];

    f32x4 acc[2][16];
#pragma unroll
    for (int m = 0; m < 2; ++m)
#pragma unroll
        for (int n = 0; n < 16; ++n) acc[m][n] = (f32x4){0.f, 0.f, 0.f, 0.f};

    const int sr = tid >> 1;
    const int sh = (tid & 1) * 16;
    const float rv = rinv[b * 256 + sr];
    const float* hrow = H + ((size_t)b * 256 + sr) * 512;

    for (int kc = 0; kc < 16; ++kc) {
        if (kc) __syncthreads();
        {
            const float4* src = (const float4*)(hrow + kc * 32 + sh);
#pragma unroll
            for (int i = 0; i < 4; ++i) {
                float4 v = src[i];
                float vv[4] = {v.x, v.y, v.z, v.w};
                ushort4 h4, l4v;
                unsigned short* hp = (unsigned short*)&h4;
                unsigned short* lp = (unsigned short*)&l4v;
#pragma unroll
                for (int e = 0; e < 4; ++e) {
                    const float x = vv[e] * rv;
                    const __half hi = __float2half(x);
                    const __half lo = __float2half((x - __half2float(hi)) * LO_SCALE);
                    hp[e] = __half_as_ushort(hi);
                    lp[e] = __half_as_ushort(lo);
                }
                *(ushort4*)&st[0][sr][sh + i * 4] = h4;
                *(ushort4*)&st[1][sr][sh + i * 4] = l4v;
            }
        }
        __syncthreads();

        f16x8 ahi[2], alo[2];
#pragma unroll
        for (int m = 0; m < 2; ++m) {
            const int row = (w * 2 + m) * 16 + l15;
            ahi[m] = *(const f16x8*)&st[0][row][l4 * 8];
            alo[m] = *(const f16x8*)&st[1][row][l4 * 8];
        }
#pragma unroll
        for (int nt = 0; nt < 16; ++nt) {
            const int col = nt * 16 + l15;
            const f16x8 bhi = *(const f16x8*)&st[0][col][l4 * 8];
            const f16x8 blo = *(const f16x8*)&st[1][col][l4 * 8];
#pragma unroll
            for (int m = 0; m < 2; ++m) {
                acc[m][nt] = MFMA16(ahi[m], bhi, acc[m][nt]);
                f32x4 t2 = (f32x4){0.f, 0.f, 0.f, 0.f};
                t2 = MFMA16(ahi[m], blo, t2);
                t2 = MFMA16(alo[m], bhi, t2);
#pragma unroll
                for (int r = 0; r < 4; ++r)
                    acc[m][nt][r] = fmaf(LO_INV, t2[r], acc[m][nt][r]);
            }
        }
    }

#pragma unroll
    for (int m = 0; m < 2; ++m) {
        const int row0 = (w * 2 + m) * 16 + l4 * 4;
#pragma unroll
        for (int nt = 0; nt < 16; ++nt)
#pragma unroll
            for (int r = 0; r < 4; ++r)
                sim[((size_t)b * 256 + row0 + r) * 256 + nt * 16 + l15] = acc[m][nt][r];
    }
}

// ---------------- GCN layer GEMMs (MFMA fp16-split), A staged from fp32 ------------
template<int KDIM, int NDIM, int NT_PER>
__global__ __launch_bounds__(512)
void gcn_mm(const float* __restrict__ X, const unsigned short* __restrict__ pack,
            float* __restrict__ Y)
{
    const int tid = threadIdx.x;
    const int w = tid >> 6, l = tid & 63;
    const int l15 = l & 15, l4 = l >> 4;
    const int m0 = blockIdx.x * 64;
    constexpr int KC = KDIM / 32;

    __shared__ unsigned short a[2][64 * KDIM];

    {
        const int row = tid >> 3;
        const int seg = (tid & 7) * (KDIM / 8);
        const float4* src = (const float4*)(X + (size_t)(m0 + row) * KDIM + seg);
        const int sw = (row & 7) << 3;
#pragma unroll
        for (int i = 0; i < KDIM / 32; ++i) {
            float4 v = src[i];
            float vv[4] = {v.x, v.y, v.z, v.w};
#pragma unroll
            for (int e = 0; e < 4; ++e) {
                const float x = vv[e];
                const __half hi = __float2half(x);
                const __half lo = __float2half((x - __half2float(hi)) * LO_SCALE);
                const int ad = row * KDIM + ((seg + i * 4 + e) ^ sw);
                a[0][ad] = __half_as_ushort(hi);
                a[1][ad] = __half_as_ushort(lo);
            }
        }
    }
    __syncthreads();

    const int mt = w >> 1, nh = w & 1;
    f32x4 acc[NT_PER];
#pragma unroll
    for (int i = 0; i < NT_PER; ++i) acc[i] = (f32x4){0.f, 0.f, 0.f, 0.f};

    const int arow = mt * 16 + l15;
    const int abase = arow * KDIM;
    const int asw = (arow & 7) << 3;

#pragma unroll
    for (int kc = 0; kc < KC; ++kc) {
        const int ad = abase + ((kc * 32 + l4 * 8) ^ asw);
        const f16x8 ahi = *(const f16x8*)&a[0][ad];
        const f16x8 alo = *(const f16x8*)&a[1][ad];
#pragma unroll
        for (int ntl = 0; ntl < NT_PER; ++ntl) {
            const int nt = nh * NT_PER + ntl;
            const uint4* bp = (const uint4*)(pack + ((size_t)(nt * KC + kc) * 2) * 512);
            uint4 bh4 = bp[l];
            uint4 bl4 = bp[64 + l];
            const f16x8 Bhi = *reinterpret_cast<const f16x8*>(&bh4);
            const f16x8 Blo = *reinterpret_cast<const f16x8*>(&bl4);
            acc[ntl] = MFMA16(ahi, Bhi, acc[ntl]);
            f32x4 t2 = (f32x4){0.f, 0.f, 0.f, 0.f};
            t2 = MFMA16(ahi, Blo, t2);
            t2 = MFMA16(alo, Bhi, t2);
#pragma unroll
            for (int r = 0; r < 4; ++r) acc[ntl][r] = fmaf(LO_INV, t2[r], acc[ntl][r]);
        }
    }

#pragma unroll
    for (int ntl = 0; ntl < NT_PER; ++ntl) {
        const int n = (nh * NT_PER + ntl) * 16 + l15;
#pragma unroll
        for (int r = 0; r < 4; ++r) {
            const int m = m0 + mt * 16 + l4 * 4 + r;
            Y[(size_t)m * NDIM + n] = acc[ntl][r];
        }
    }
}

// ---------------- top-5 per sim row (strict >, jax lower-index tie behavior) ------
__global__ __launch_bounds__(256)
void topk5(const float* __restrict__ sim, int* __restrict__ idx)
{
    const int row = blockIdx.x * 256 + threadIdx.x;
    const float* p = sim + (size_t)row * 256;
    float bv0 = -1e30f, bv1 = -1e30f, bv2 = -1e30f, bv3 = -1e30f, bv4 = -1e30f;
    int   bi0 = 0, bi1 = 0, bi2 = 0, bi3 = 0, bi4 = 0;
    for (int m4 = 0; m4 < 64; ++m4) {
        float4 v4 = *(const float4*)(p + m4 * 4);
        float vv[4] = {v4.x, v4.y, v4.z, v4.w};
#pragma unroll
        for (int c = 0; c < 4; ++c) {
            float v = vv[c];
            int   m = m4 * 4 + c;
            if (v > bv0) {
                if (v > bv1) {
                    bv0 = bv1; bi0 = bi1;
                    if (v > bv2) {
                        bv1 = bv2; bi1 = bi2;
                        if (v > bv3) {
                            bv2 = bv3; bi2 = bi3;
                            if (v > bv4) { bv3 = bv4; bi3 = bi4; bv4 = v; bi4 = m; }
                            else         { bv3 = v;  bi3 = m; }
                        } else { bv2 = v; bi2 = m; }
                    } else { bv1 = v; bi1 = m; }
                } else { bv0 = v; bi0 = m; }
            }
        }
    }
    int* o = idx + (size_t)row * 5;
    o[0] = bi0; o[1] = bi1; o[2] = bi2; o[3] = bi3; o[4] = bi4;
}

// ---------------- sparse GCN aggregation: out[n] = c*(X[n] + sum_j X[idx_j]) ------
template<bool RELU, int DIM>
__global__ __launch_bounds__(128)
void gcn_agg(const float* __restrict__ X, const int* __restrict__ idxs,
             float* __restrict__ outp, float cnorm)
{
    const int row = blockIdx.x;
    const int bbase = row & ~255;
    const int* id = idxs + (size_t)row * 5;
    const int i0 = bbase + id[0];
    const int i1 = bbase + id[1];
    const int i2 = bbase + id[2];
    const int i3 = bbase + id[3];
    const int i4 = bbase + id[4];
    const int t = threadIdx.x;
    if (DIM == 512) {
        const float4* Xp = (const float4*)X;
        float4 a = Xp[(size_t)row * 128 + t];
        float4 v;
        v = Xp[(size_t)i0 * 128 + t]; a.x += v.x; a.y += v.y; a.z += v.z; a.w += v.w;
        v = Xp[(size_t)i1 * 128 + t]; a.x += v.x; a.y += v.y; a.z += v.z; a.w += v.w;
        v = Xp[(size_t)i2 * 128 + t]; a.x += v.x; a.y += v.y; a.z += v.z; a.w += v.w;
        v = Xp[(size_t)i3 * 128 + t]; a.x += v.x; a.y += v.y; a.z += v.z; a.w += v.w;
        v = Xp[(size_t)i4 * 128 + t]; a.x += v.x; a.y += v.y; a.z += v.z; a.w += v.w;
        a.x *= cnorm; a.y *= cnorm; a.z *= cnorm; a.w *= cnorm;
        if (RELU) {
            a.x = fmaxf(a.x, 0.f); a.y = fmaxf(a.y, 0.f);
            a.z = fmaxf(a.z, 0.f); a.w = fmaxf(a.w, 0.f);
        }
        ((float4*)outp)[(size_t)row * 128 + t] = a;
    } else {
        float a = X[(size_t)row * 128 + t];
        a += X[(size_t)i0 * 128 + t];
        a += X[(size_t)i1 * 128 + t];
        a += X[(size_t)i2 * 128 + t];
        a += X[(size_t)i3 * 128 + t];
        a += X[(size_t)i4 * 128 + t];
        a *= cnorm;
        if (RELU) a = fmaxf(a, 0.f);
        outp[(size_t)row * 128 + t] = a;
    }
}

// ------------------------------- launcher -----------------------------------------
extern "C" void kernel_launch(void* const* d_in, const int* in_sizes, int n_in,
                              void* d_out, int out_size, void* d_ws, size_t ws_size,
                              hipStream_t stream)
{
    (void)in_sizes; (void)n_in; (void)out_size; (void)ws_size;

    const float* C_masked = (const float*)d_in[0];
    const float* W_proj   = (const float*)d_in[1];
    const float* b_proj   = (const float*)d_in[2];
    const float* Wih_f    = (const float*)d_in[3];
    const float* Whh_f    = (const float*)d_in[4];
    const float* bih_f    = (const float*)d_in[5];
    const float* bhh_f    = (const float*)d_in[6];
    const float* Wih_b    = (const float*)d_in[7];
    const float* Whh_b    = (const float*)d_in[8];
    const float* bih_b    = (const float*)d_in[9];
    const float* bhh_b    = (const float*)d_in[10];
    const float* W_gcn1   = (const float*)d_in[11];
    const float* W_gcn2   = (const float*)d_in[12];
    float* out = (float*)d_out;

    char* ws = (char*)d_ws;
    size_t o = 0;
    auto take = [&](size_t bytes) {
        size_t r = o;
        o = (o + bytes + 255) & ~(size_t)255;
        return r;
    };
    const size_t WCOMB_B = (size_t)768 * 256 * 4;
    const size_t PACK_B  = (size_t)48 * 8 * 2 * 512 * 2;   // 786432
    const size_t PACKG_B = (size_t)262144;
    const size_t o_wcf  = take(WCOMB_B);
    const size_t o_wcb  = take(WCOMB_B);
    const size_t o_bcf  = take(768 * 4);
    const size_t o_bcb  = take(768 * 4);
    const size_t o_rinv = take((size_t)65536 * 4);
    const size_t o_topk = take((size_t)65536 * 5 * 4);
    const size_t o_pwf  = take(PACK_B);
    const size_t o_pwb  = take(PACK_B);
    const size_t o_phf  = take(PACK_B);     // scan weight pack fwd
    const size_t o_phb  = take(PACK_B);     // scan weight pack bwd
    const size_t o_pg1  = take(PACKG_B);
    const size_t o_pg2  = take(PACKG_B);
    const size_t o_hx   = take((size_t)32 * 2 * 8 * 256 * 4);  // 512 KB h exchange
    const size_t o_cnt  = take((size_t)2 * 32 * 4);            // counters (both dirs)
    const size_t regionA = o;

    const size_t GI_BYTES = (size_t)65536 * 768 * 4;   // 201,326,592

    float* wcomb_f = (float*)(ws + o_wcf);
    float* wcomb_b = (float*)(ws + o_wcb);
    float* bcomb_f = (float*)(ws + o_bcf);
    float* bcomb_b = (float*)(ws + o_bcb);
    float* rinv    = (float*)(ws + o_rinv);
    int*   topk    = (int*)(ws + o_topk);
    unsigned short* packWf = (unsigned short*)(ws + o_pwf);
    unsigned short* packWb = (unsigned short*)(ws + o_pwb);
    unsigned short* packHf = (unsigned short*)(ws + o_phf);
    unsigned short* packHb = (unsigned short*)(ws + o_phb);
    unsigned short* packG1 = (unsigned short*)(ws + o_pg1);
    unsigned short* packG2 = (unsigned short*)(ws + o_pg2);
    float* hx = (float*)(ws + o_hx);
    unsigned int* cntF = (unsigned int*)(ws + o_cnt);
    unsigned int* cntB = cntF + 32;

    float* gi   = (float*)(ws + regionA);
    float* Hbuf = (float*)(ws + regionA + GI_BYTES);

    float* sim  = (float*)(ws + regionA);               // 67,108,864 B
    float* XW1  = (float*)(ws + regionA + 67108864);    // 33,554,432 B
    float* Z1   = (float*)(ws + regionA + 167772160);   // 33,554,432 B
    float* Z1W2 = (float*)(ws + regionA);               // 134,217,728 B

    const dim3 blk(256);

    // 1. combined weights + biases; packs (gi weights, scan weights, GCN weights)
    gemm_f32<false><<<dim3(2, 6, 1), blk, 0, stream>>>(
        768, 256, 512, Wih_f, 0, W_proj, 0, wcomb_f, 0, nullptr, nullptr, nullptr);
    gemm_f32<false><<<dim3(2, 6, 1), blk, 0, stream>>>(
        768, 256, 512, Wih_b, 0, W_proj, 0, wcomb_b, 0, nullptr, nullptr, nullptr);
    bias_combine<<<3, 256, 0, stream>>>(Wih_f, b_proj, bih_f, bcomb_f);
    bias_combine<<<3, 256, 0, stream>>>(Wih_b, b_proj, bih_b, bcomb_b);
    pack_w<<<768, 256, 0, stream>>>(wcomb_f, packWf);
    pack_w<<<768, 256, 0, stream>>>(wcomb_b, packWb);
    pack_w<<<768, 256, 0, stream>>>(Whh_f, packHf);
    pack_w<<<768, 256, 0, stream>>>(Whh_b, packHb);
    pack_bk<<<256, 256, 0, stream>>>(W_gcn1, packG1, 512, 128);
    pack_bk<<<256, 256, 0, stream>>>(W_gcn2, packG2, 128, 512);
    hipMemsetAsync(cntF, 0, 2 * 32 * 4, stream);

    // 2. gi GEMM + scan, per direction (sequential; gi buffer reused)
    gi_gemm<<<1024, 512, 0, stream>>>(C_masked, packWf, bcomb_f, gi);
    gru_scan_v7<<<256, 512, 0, stream>>>(gi, packHf, bhh_f, Hbuf, hx, cntF, 0);
    gi_gemm<<<1024, 512, 0, stream>>>(C_masked, packWb, bcomb_b, gi);
    gru_scan_v7<<<256, 512, 0, stream>>>(gi, packHb, bhh_b, Hbuf, hx, cntB, 1);

    // 3. cosine-sim (MFMA, rinv folded) -> top-5
    rownorm<<<16384, blk, 0, stream>>>(Hbuf, rinv);
    sim_mfma<<<256, 512, 0, stream>>>(Hbuf, rinv, sim);
    topk5<<<256, blk, 0, stream>>>(sim, topk);

    // 4. GCN with A_norm = A / (6 + 1e-8)  (row-sum of A is always K+1 = 6)
    const float cnorm = (float)(1.0 / (6.0 + 1e-8));
    gcn_mm<512, 128, 4><<<1024, 512, 0, stream>>>(Hbuf, packG1, XW1);
    gcn_agg<true, 128><<<65536, 128, 0, stream>>>(XW1, topk, Z1, cnorm);
    gcn_mm<128, 512, 16><<<1024, 512, 0, stream>>>(Z1, packG2, Z1W2);
    gcn_agg<false, 512><<<65536, 128, 0, stream>>>(Z1W2, topk, out, cnorm);
}

// Round 8
// 5988.070 us; speedup vs baseline: 3.9809x; 3.9809x over previous
//
#include <hip/hip_runtime.h>
#include <hip/hip_fp16.h>
#include <cstdint>
#include <cmath>

typedef _Float16 f16x8 __attribute__((ext_vector_type(8)));
typedef float f32x4 __attribute__((ext_vector_type(4)));

#define MFMA16(A, B, C) __builtin_amdgcn_mfma_f32_16x16x32_f16(A, B, C, 0, 0, 0)
#define LO_SCALE 2048.0f
#define LO_INV   4.8828125e-4f

// ---------------- fp32 tiled GEMM (kept only for the tiny wcomb GEMMs) ------------
#define GBM 128
#define GBN 128
#define GBK 16

template<bool TRANSB>
__global__ __launch_bounds__(256)
void gemm_f32(int M, int N, int K,
              const float* __restrict__ A, long long sA,
              const float* __restrict__ B, long long sB,
              float* __restrict__ Cc, long long sC,
              const float* __restrict__ bias,
              const float* __restrict__ rsA,
              const float* __restrict__ rsB)
{
    const int z = blockIdx.z;
    A  += (size_t)z * (size_t)sA;
    B  += (size_t)z * (size_t)sB;
    Cc += (size_t)z * (size_t)sC;

    const int bm = blockIdx.y * GBM;
    const int bn = blockIdx.x * GBN;
    const int tid = threadIdx.x;
    const int tx = tid & 15;
    const int ty = tid >> 4;

    __shared__ float As[GBK][GBM + 4];
    __shared__ float Bs[GBK][GBN + 4];

    float acc[8][8];
#pragma unroll
    for (int i = 0; i < 8; ++i)
#pragma unroll
        for (int j = 0; j < 8; ++j) acc[i][j] = 0.0f;

    const int lr = tid >> 2;
    const int lk = (tid & 3) << 2;
    const int kb_n = tid >> 5;
    const int nb_n = (tid & 31) << 2;

    float sa0 = 1.f, sa1 = 1.f, sb0 = 1.f, sb1 = 1.f;
    if (rsA) {
        sa0 = rsA[(size_t)z * M + bm + lr];
        sa1 = rsA[(size_t)z * M + bm + lr + 64];
    }
    if (TRANSB && rsB) {
        sb0 = rsB[(size_t)z * N + bn + lr];
        sb1 = rsB[(size_t)z * N + bn + lr + 64];
    }

    float4 pa0, pa1, pb0, pb1;

    auto gload = [&](int kt) {
        const float* pA = A + (size_t)(bm + lr) * K + kt * GBK + lk;
        pa0 = *(const float4*)pA;
        pa1 = *(const float4*)(pA + (size_t)64 * K);
        if (TRANSB) {
            const float* pB = B + (size_t)(bn + lr) * K + kt * GBK + lk;
            pb0 = *(const float4*)pB;
            pb1 = *(const float4*)(pB + (size_t)64 * K);
        } else {
            const float* pB = B + (size_t)(kt * GBK + kb_n) * N + bn + nb_n;
            pb0 = *(const float4*)pB;
            pb1 = *(const float4*)(pB + (size_t)8 * N);
        }
    };
    auto sstore = [&]() {
        As[lk + 0][lr] = pa0.x * sa0; As[lk + 1][lr] = pa0.y * sa0;
        As[lk + 2][lr] = pa0.z * sa0; As[lk + 3][lr] = pa0.w * sa0;
        As[lk + 0][lr + 64] = pa1.x * sa1; As[lk + 1][lr + 64] = pa1.y * sa1;
        As[lk + 2][lr + 64] = pa1.z * sa1; As[lk + 3][lr + 64] = pa1.w * sa1;
        if (TRANSB) {
            Bs[lk + 0][lr] = pb0.x * sb0; Bs[lk + 1][lr] = pb0.y * sb0;
            Bs[lk + 2][lr] = pb0.z * sb0; Bs[lk + 3][lr] = pb0.w * sb0;
            Bs[lk + 0][lr + 64] = pb1.x * sb1; Bs[lk + 1][lr + 64] = pb1.y * sb1;
            Bs[lk + 2][lr + 64] = pb1.z * sb1; Bs[lk + 3][lr + 64] = pb1.w * sb1;
        } else {
            *(float4*)&Bs[kb_n][nb_n]     = pb0;
            *(float4*)&Bs[kb_n + 8][nb_n] = pb1;
        }
    };

    const int nkt = K / GBK;
    gload(0);
    sstore();
    __syncthreads();
    for (int kt = 0; kt < nkt; ++kt) {
        if (kt + 1 < nkt) gload(kt + 1);
#pragma unroll
        for (int k = 0; k < GBK; ++k) {
            float4 a0 = *(const float4*)&As[k][ty * 8];
            float4 a1 = *(const float4*)&As[k][ty * 8 + 4];
            float4 b0 = *(const float4*)&Bs[k][tx * 8];
            float4 b1 = *(const float4*)&Bs[k][tx * 8 + 4];
            float av[8] = {a0.x, a0.y, a0.z, a0.w, a1.x, a1.y, a1.z, a1.w};
            float bv[8] = {b0.x, b0.y, b0.z, b0.w, b1.x, b1.y, b1.z, b1.w};
#pragma unroll
            for (int i = 0; i < 8; ++i)
#pragma unroll
                for (int j = 0; j < 8; ++j)
                    acc[i][j] = fmaf(av[i], bv[j], acc[i][j]);
        }
        __syncthreads();
        if (kt + 1 < nkt) { sstore(); __syncthreads(); }
    }

    float bb[8];
#pragma unroll
    for (int j = 0; j < 8; ++j) bb[j] = bias ? bias[bn + tx * 8 + j] : 0.0f;
#pragma unroll
    for (int i = 0; i < 8; ++i) {
        const int row = bm + ty * 8 + i;
        float* cp = Cc + (size_t)row * N + bn + tx * 8;
        float4 o0 = make_float4(acc[i][0] + bb[0], acc[i][1] + bb[1],
                                acc[i][2] + bb[2], acc[i][3] + bb[3]);
        float4 o1 = make_float4(acc[i][4] + bb[4], acc[i][5] + bb[5],
                                acc[i][6] + bb[6], acc[i][7] + bb[7]);
        *(float4*)cp = o0;
        *(float4*)(cp + 4) = o1;
    }
}

// ---------------- combined GRU input bias: bcomb = bih + Wih @ b_proj --------------
__global__ void bias_combine(const float* __restrict__ Wih, const float* __restrict__ b_proj,
                             const float* __restrict__ bih, float* __restrict__ bcomb)
{
    const int j = blockIdx.x * blockDim.x + threadIdx.x;
    if (j >= 768) return;
    float s = bih[j];
    for (int k = 0; k < 512; ++k) s = fmaf(Wih[(size_t)j * 512 + k], b_proj[k], s);
    bcomb[j] = s;
}

// ---------------- pack W[N=768][K=256] into MFMA fp16-split B-fragments ------------
__global__ __launch_bounds__(256)
void pack_w(const float* __restrict__ W, unsigned short* __restrict__ pack)
{
    const int idx = blockIdx.x * 256 + threadIdx.x;
    if (idx >= 768 * 256) return;
    const int n = idx >> 8;
    const int k = idx & 255;
    const float w = W[idx];
    const __half hi = __float2half(w);
    const __half lo = __float2half((w - __half2float(hi)) * LO_SCALE);
    const int nt = n >> 4;
    const int lane = ((k >> 3) & 3) * 16 + (n & 15);
    const int j = k & 7;
    const int kc = k >> 5;
    const size_t base = ((size_t)(nt * 8 + kc) * 2) * 512 + lane * 8 + j;
    pack[base]       = __half_as_ushort(hi);
    pack[base + 512] = __half_as_ushort(lo);
}

// ---------------- pack W[K][N] (row-major) into MFMA fp16-split fragments ----------
__global__ __launch_bounds__(256)
void pack_bk(const float* __restrict__ W, unsigned short* __restrict__ pack,
             int K, int N)
{
    const int idx = blockIdx.x * 256 + threadIdx.x;
    if (idx >= K * N) return;
    const int k = idx / N;
    const int n = idx - k * N;
    const float w = W[idx];
    const __half hi = __float2half(w);
    const __half lo = __float2half((w - __half2float(hi)) * LO_SCALE);
    const int nt = n >> 4;
    const int kc = k >> 5;
    const int lane = ((k >> 3) & 3) * 16 + (n & 15);
    const int j = k & 7;
    const int KC = K >> 5;
    const size_t base = ((size_t)(nt * KC + kc) * 2) * 512 + lane * 8 + j;
    pack[base]       = __half_as_ushort(hi);
    pack[base + 512] = __half_as_ushort(lo);
}

// ---------------- gi GEMM chunk (MFMA fp16-split): t-slice [t0, t0+128) ------------
// Output chunk layout: gi[((b*128) + (s - t0))*768 + n]. grid = 512 blocks.
__global__ __launch_bounds__(512)
void gi_gemm_c(const float* __restrict__ Cm, const unsigned short* __restrict__ pack,
               const float* __restrict__ bcomb, float* __restrict__ gi, int t0)
{
    const int tid = threadIdx.x;
    const int w = tid >> 6, l = tid & 63;
    const int l15 = l & 15, l4 = l >> 4;
    const int bgrp = blockIdx.x >> 1;            // batch 0..255
    const int half = blockIdx.x & 1;             // 64-row half of the chunk
    const size_t m0 = (size_t)bgrp * 256 + t0 + half * 64;   // global C row
    const size_t o0 = (size_t)bgrp * 128 + half * 64;        // chunk-local out row

    __shared__ unsigned short alds[2][64 * 256];

    {   // stage A tile: fp32 -> fp16 hi/lo planes with XOR swizzle
        const int row = tid >> 3;
        const int seg = (tid & 7) * 32;
        const float4* src = (const float4*)(Cm + (m0 + row) * 256 + seg);
        const int sw = (row & 7) << 3;
#pragma unroll
        for (int i = 0; i < 8; ++i) {
            float4 v = src[i];
            float vv[4] = {v.x, v.y, v.z, v.w};
#pragma unroll
            for (int e = 0; e < 4; ++e) {
                const float x = vv[e];
                const __half hi = __float2half(x);
                const __half lo = __float2half((x - __half2float(hi)) * LO_SCALE);
                const int ad = (row << 8) + ((seg + i * 4 + e) ^ sw);
                alds[0][ad] = __half_as_ushort(hi);
                alds[1][ad] = __half_as_ushort(lo);
            }
        }
    }
    __syncthreads();

    const int mt = w >> 1, nh = w & 1;
    f32x4 acc[24];
#pragma unroll
    for (int i = 0; i < 24; ++i) acc[i] = (f32x4){0.f, 0.f, 0.f, 0.f};

    const int ar = mt * 16 + l15;
    const int arow = ar << 8;
    const int asw = (ar & 7) << 3;

#pragma unroll
    for (int kc = 0; kc < 8; ++kc) {
        const int ad = arow + ((kc * 32 + l4 * 8) ^ asw);
        const f16x8 ahi = *(const f16x8*)&alds[0][ad];
        const f16x8 alo = *(const f16x8*)&alds[1][ad];
#pragma unroll
        for (int nt = 0; nt < 24; ++nt) {
            const int nt_lin = nh * 24 + nt;
            const uint4* bp = (const uint4*)(pack + ((size_t)(nt_lin * 8 + kc) * 2) * 512);
            uint4 bh4 = bp[l];
            uint4 bl4 = bp[64 + l];
            const f16x8 Bhi = *reinterpret_cast<const f16x8*>(&bh4);
            const f16x8 Blo = *reinterpret_cast<const f16x8*>(&bl4);
            acc[nt] = MFMA16(ahi, Bhi, acc[nt]);
            f32x4 t2 = (f32x4){0.f, 0.f, 0.f, 0.f};
            t2 = MFMA16(ahi, Blo, t2);
            t2 = MFMA16(alo, Bhi, t2);
#pragma unroll
            for (int r = 0; r < 4; ++r) acc[nt][r] = fmaf(LO_INV, t2[r], acc[nt][r]);
        }
    }

#pragma unroll
    for (int nt = 0; nt < 24; ++nt) {
        const int n = (nh * 24 + nt) * 16 + l15;
        const float bb = bcomb[n];
#pragma unroll
        for (int r = 0; r < 4; ++r) {
            const size_t om = o0 + mt * 16 + l4 * 4 + r;
            __builtin_nontemporal_store(acc[nt][r] + bb, &gi[om * 768 + n]);
        }
    }
}

// ---------------- GRU scan v8: R4's v4 core, time-chunked, bidirectional par -------
// 128 blocks x 1024 threads, one phase = 128 steps. dir pinned per XCD-half
// (bid&7 >> 2); grp covers 64 batch-groups of G=4 per dir. Thread (j=tid>>2,
// q=tid&3): Whh rows {j,j+256,j+512}, k-slice {u*16+q*4}, owns batch b0+q.
// gi read from the direction's 128-step chunk (chunk-local index). h checkpoint
// in hstate between phases. gi/H non-temporal so streams don't evict weights.
__global__ __launch_bounds__(1024)
void gru_scan_v8(const float* __restrict__ gi_fc, const float* __restrict__ gi_bc,
                 const float* __restrict__ Whh_f, const float* __restrict__ Whh_b,
                 const float* __restrict__ bhh_f, const float* __restrict__ bhh_b,
                 float* __restrict__ H, float* __restrict__ hstate, int phase)
{
    const int bid = blockIdx.x;
    const int xcd = bid & 7;
    const int dir = xcd >> 2;
    const int grp = (bid >> 3) * 4 + (xcd & 3);   // 0..63
    const float* __restrict__ gi  = dir ? gi_bc : gi_fc;
    const float* __restrict__ Whh = dir ? Whh_b : Whh_f;
    const float* __restrict__ bhh = dir ? bhh_b : bhh_f;
    const int b0 = grp * 4;
    const int t0 = dir ? (128 - phase * 128) : (phase * 128);

    const int tid = threadIdx.x;
    const int j = tid >> 2;    // unit 0..255
    const int q = tid & 3;     // k-quarter / owned batch

    __shared__ float hb[2][4][256];

    float hreg = (phase == 0)
        ? 0.0f
        : hstate[((size_t)dir * 256 + b0 + q) * 256 + j];
    hb[0][q][j] = hreg;

    const float bh_r = bhh[j], bh_z = bhh[j + 256], bh_n = bhh[j + 512];

    const float* __restrict__ Wr = Whh + (size_t)j * 256 + q * 4;
    const float* __restrict__ Wz = Whh + (size_t)(j + 256) * 256 + q * 4;
    const float* __restrict__ Wn = Whh + (size_t)(j + 512) * 256 + q * 4;

    __syncthreads();

    int p = 0;
    for (int tau = 0; tau < 128; ++tau) {
        const int sc = dir ? (127 - tau) : tau;    // chunk-local step
        const int tt = t0 + sc;                    // global step

        // gi for own batch (non-temporal)
        const float* gp = gi + ((size_t)(b0 + q) * 128 + sc) * 768 + j;
        const float g_r = __builtin_nontemporal_load(gp);
        const float g_z = __builtin_nontemporal_load(gp + 256);
        const float g_n = __builtin_nontemporal_load(gp + 512);

        float ar0 = 0.f, ar1 = 0.f, ar2 = 0.f, ar3 = 0.f;
        float az0 = 0.f, az1 = 0.f, az2 = 0.f, az3 = 0.f;
        float an0 = 0.f, an1 = 0.f, an2 = 0.f, an3 = 0.f;
#pragma unroll
        for (int u = 0; u < 16; ++u) {
            const float4 wr = *(const float4*)(Wr + u * 16);
            const float4 wz = *(const float4*)(Wz + u * 16);
            const float4 wn = *(const float4*)(Wn + u * 16);
            const int ha = u * 16 + q * 4;
            const float4 h0 = *(const float4*)&hb[p][0][ha];
            const float4 h1 = *(const float4*)&hb[p][1][ha];
            const float4 h2 = *(const float4*)&hb[p][2][ha];
            const float4 h3 = *(const float4*)&hb[p][3][ha];
            ar0 = fmaf(wr.x, h0.x, ar0); ar0 = fmaf(wr.y, h0.y, ar0);
            ar0 = fmaf(wr.z, h0.z, ar0); ar0 = fmaf(wr.w, h0.w, ar0);
            ar1 = fmaf(wr.x, h1.x, ar1); ar1 = fmaf(wr.y, h1.y, ar1);
            ar1 = fmaf(wr.z, h1.z, ar1); ar1 = fmaf(wr.w, h1.w, ar1);
            ar2 = fmaf(wr.x, h2.x, ar2); ar2 = fmaf(wr.y, h2.y, ar2);
            ar2 = fmaf(wr.z, h2.z, ar2); ar2 = fmaf(wr.w, h2.w, ar2);
            ar3 = fmaf(wr.x, h3.x, ar3); ar3 = fmaf(wr.y, h3.y, ar3);
            ar3 = fmaf(wr.z, h3.z, ar3); ar3 = fmaf(wr.w, h3.w, ar3);
            az0 = fmaf(wz.x, h0.x, az0); az0 = fmaf(wz.y, h0.y, az0);
            az0 = fmaf(wz.z, h0.z, az0); az0 = fmaf(wz.w, h0.w, az0);
            az1 = fmaf(wz.x, h1.x, az1); az1 = fmaf(wz.y, h1.y, az1);
            az1 = fmaf(wz.z, h1.z, az1); az1 = fmaf(wz.w, h1.w, az1);
            az2 = fmaf(wz.x, h2.x, az2); az2 = fmaf(wz.y, h2.y, az2);
            az2 = fmaf(wz.z, h2.z, az2); az2 = fmaf(wz.w, h2.w, az2);
            az3 = fmaf(wz.x, h3.x, az3); az3 = fmaf(wz.y, h3.y, az3);
            az3 = fmaf(wz.z, h3.z, az3); az3 = fmaf(wz.w, h3.w, az3);
            an0 = fmaf(wn.x, h0.x, an0); an0 = fmaf(wn.y, h0.y, an0);
            an0 = fmaf(wn.z, h0.z, an0); an0 = fmaf(wn.w, h0.w, an0);
            an1 = fmaf(wn.x, h1.x, an1); an1 = fmaf(wn.y, h1.y, an1);
            an1 = fmaf(wn.z, h1.z, an1); an1 = fmaf(wn.w, h1.w, an1);
            an2 = fmaf(wn.x, h2.x, an2); an2 = fmaf(wn.y, h2.y, an2);
            an2 = fmaf(wn.z, h2.z, an2); an2 = fmaf(wn.w, h2.w, an2);
            an3 = fmaf(wn.x, h3.x, an3); an3 = fmaf(wn.y, h3.y, an3);
            an3 = fmaf(wn.z, h3.z, an3); an3 = fmaf(wn.w, h3.w, an3);
        }

        // butterfly over q (lanes xor 1, 2)
        ar0 += __shfl_xor(ar0, 1); ar0 += __shfl_xor(ar0, 2);
        ar1 += __shfl_xor(ar1, 1); ar1 += __shfl_xor(ar1, 2);
        ar2 += __shfl_xor(ar2, 1); ar2 += __shfl_xor(ar2, 2);
        ar3 += __shfl_xor(ar3, 1); ar3 += __shfl_xor(ar3, 2);
        az0 += __shfl_xor(az0, 1); az0 += __shfl_xor(az0, 2);
        az1 += __shfl_xor(az1, 1); az1 += __shfl_xor(az1, 2);
        az2 += __shfl_xor(az2, 1); az2 += __shfl_xor(az2, 2);
        az3 += __shfl_xor(az3, 1); az3 += __shfl_xor(az3, 2);
        an0 += __shfl_xor(an0, 1); an0 += __shfl_xor(an0, 2);
        an1 += __shfl_xor(an1, 1); an1 += __shfl_xor(an1, 2);
        an2 += __shfl_xor(an2, 1); an2 += __shfl_xor(an2, 2);
        an3 += __shfl_xor(an3, 1); an3 += __shfl_xor(an3, 2);

        const float pr = (q == 0) ? ar0 : (q == 1) ? ar1 : (q == 2) ? ar2 : ar3;
        const float pz = (q == 0) ? az0 : (q == 1) ? az1 : (q == 2) ? az2 : az3;
        const float pn = (q == 0) ? an0 : (q == 1) ? an1 : (q == 2) ? an2 : an3;

        const float rr = 1.0f / (1.0f + expf(-(g_r + pr + bh_r)));
        const float zz = 1.0f / (1.0f + expf(-(g_z + pz + bh_z)));
        const float nn = tanhf(g_n + rr * (pn + bh_n));
        hreg = (1.0f - zz) * nn + zz * hreg;

        hb[p ^ 1][q][j] = hreg;
        __builtin_nontemporal_store(
            hreg, &H[((size_t)(b0 + q) * 256 + tt) * 512 + dir * 256 + j]);
        __syncthreads();
        p ^= 1;
    }

    hstate[((size_t)dir * 256 + b0 + q) * 256 + j] = hreg;
}

// ---------------- row 1/max(norm,1e-12) for cosine normalization ------------------
__global__ __launch_bounds__(256)
void rownorm(const float* __restrict__ H, float* __restrict__ rinv)
{
    const int row  = blockIdx.x * 4 + (threadIdx.x >> 6);
    const int lane = threadIdx.x & 63;
    const float4* p = (const float4*)(H + (size_t)row * 512);
    float ss = 0.f;
    float4 v = p[lane];
    ss += v.x * v.x + v.y * v.y + v.z * v.z + v.w * v.w;
    v = p[lane + 64];
    ss += v.x * v.x + v.y * v.y + v.z * v.z + v.w * v.w;
#pragma unroll
    for (int off = 32; off >= 1; off >>= 1) ss += __shfl_xor(ss, off);
    if (lane == 0) rinv[row] = 1.0f / fmaxf(sqrtf(ss), 1e-12f);
}

// ---------------- sim (MFMA fp16-split, batched 256x256x512, rinv folded) ----------
__global__ __launch_bounds__(512)
void sim_mfma(const float* __restrict__ H, const float* __restrict__ rinv,
              float* __restrict__ sim)
{
    const int b = blockIdx.x;
    const int tid = threadIdx.x;
    const int w = tid >> 6, l = tid & 63;
    const int l15 = l & 15, l4 = l >> 4;

    __shared__ unsigned short st[2][256][40];

    f32x4 acc[2][16];
#pragma unroll
    for (int m = 0; m < 2; ++m)
#pragma unroll
        for (int n = 0; n < 16; ++n) acc[m][n] = (f32x4){0.f, 0.f, 0.f, 0.f};

    const int sr = tid >> 1;
    const int sh = (tid & 1) * 16;
    const float rv = rinv[b * 256 + sr];
    const float* hrow = H + ((size_t)b * 256 + sr) * 512;

    for (int kc = 0; kc < 16; ++kc) {
        if (kc) __syncthreads();
        {
            const float4* src = (const float4*)(hrow + kc * 32 + sh);
#pragma unroll
            for (int i = 0; i < 4; ++i) {
                float4 v = src[i];
                float vv[4] = {v.x, v.y, v.z, v.w};
                ushort4 h4, l4v;
                unsigned short* hp = (unsigned short*)&h4;
                unsigned short* lp = (unsigned short*)&l4v;
#pragma unroll
                for (int e = 0; e < 4; ++e) {
                    const float x = vv[e] * rv;
                    const __half hi = __float2half(x);
                    const __half lo = __float2half((x - __half2float(hi)) * LO_SCALE);
                    hp[e] = __half_as_ushort(hi);
                    lp[e] = __half_as_ushort(lo);
                }
                *(ushort4*)&st[0][sr][sh + i * 4] = h4;
                *(ushort4*)&st[1][sr][sh + i * 4] = l4v;
            }
        }
        __syncthreads();

        f16x8 ahi[2], alo[2];
#pragma unroll
        for (int m = 0; m < 2; ++m) {
            const int row = (w * 2 + m) * 16 + l15;
            ahi[m] = *(const f16x8*)&st[0][row][l4 * 8];
            alo[m] = *(const f16x8*)&st[1][row][l4 * 8];
        }
#pragma unroll
        for (int nt = 0; nt < 16; ++nt) {
            const int col = nt * 16 + l15;
            const f16x8 bhi = *(const f16x8*)&st[0][col][l4 * 8];
            const f16x8 blo = *(const f16x8*)&st[1][col][l4 * 8];
#pragma unroll
            for (int m = 0; m < 2; ++m) {
                acc[m][nt] = MFMA16(ahi[m], bhi, acc[m][nt]);
                f32x4 t2 = (f32x4){0.f, 0.f, 0.f, 0.f};
                t2 = MFMA16(ahi[m], blo, t2);
                t2 = MFMA16(alo[m], bhi, t2);
#pragma unroll
                for (int r = 0; r < 4; ++r)
                    acc[m][nt][r] = fmaf(LO_INV, t2[r], acc[m][nt][r]);
            }
        }
    }

#pragma unroll
    for (int m = 0; m < 2; ++m) {
        const int row0 = (w * 2 + m) * 16 + l4 * 4;
#pragma unroll
        for (int nt = 0; nt < 16; ++nt)
#pragma unroll
            for (int r = 0; r < 4; ++r)
                sim[((size_t)b * 256 + row0 + r) * 256 + nt * 16 + l15] = acc[m][nt][r];
    }
}

// ---------------- GCN layer GEMMs (MFMA fp16-split), A staged from fp32 ------------
template<int KDIM, int NDIM, int NT_PER>
__global__ __launch_bounds__(512)
void gcn_mm(const float* __restrict__ X, const unsigned short* __restrict__ pack,
            float* __restrict__ Y)
{
    const int tid = threadIdx.x;
    const int w = tid >> 6, l = tid & 63;
    const int l15 = l & 15, l4 = l >> 4;
    const int m0 = blockIdx.x * 64;
    constexpr int KC = KDIM / 32;

    __shared__ unsigned short a[2][64 * KDIM];

    {
        const int row = tid >> 3;
        const int seg = (tid & 7) * (KDIM / 8);
        const float4* src = (const float4*)(X + (size_t)(m0 + row) * KDIM + seg);
        const int sw = (row & 7) << 3;
#pragma unroll
        for (int i = 0; i < KDIM / 32; ++i) {
            float4 v = src[i];
            float vv[4] = {v.x, v.y, v.z, v.w};
#pragma unroll
            for (int e = 0; e < 4; ++e) {
                const float x = vv[e];
                const __half hi = __float2half(x);
                const __half lo = __float2half((x - __half2float(hi)) * LO_SCALE);
                const int ad = row * KDIM + ((seg + i * 4 + e) ^ sw);
                a[0][ad] = __half_as_ushort(hi);
                a[1][ad] = __half_as_ushort(lo);
            }
        }
    }
    __syncthreads();

    const int mt = w >> 1, nh = w & 1;
    f32x4 acc[NT_PER];
#pragma unroll
    for (int i = 0; i < NT_PER; ++i) acc[i] = (f32x4){0.f, 0.f, 0.f, 0.f};

    const int arow = mt * 16 + l15;
    const int abase = arow * KDIM;
    const int asw = (arow & 7) << 3;

#pragma unroll
    for (int kc = 0; kc < KC; ++kc) {
        const int ad = abase + ((kc * 32 + l4 * 8) ^ asw);
        const f16x8 ahi = *(const f16x8*)&a[0][ad];
        const f16x8 alo = *(const f16x8*)&a[1][ad];
#pragma unroll
        for (int ntl = 0; ntl < NT_PER; ++ntl) {
            const int nt = nh * NT_PER + ntl;
            const uint4* bp = (const uint4*)(pack + ((size_t)(nt * KC + kc) * 2) * 512);
            uint4 bh4 = bp[l];
            uint4 bl4 = bp[64 + l];
            const f16x8 Bhi = *reinterpret_cast<const f16x8*>(&bh4);
            const f16x8 Blo = *reinterpret_cast<const f16x8*>(&bl4);
            acc[ntl] = MFMA16(ahi, Bhi, acc[ntl]);
            f32x4 t2 = (f32x4){0.f, 0.f, 0.f, 0.f};
            t2 = MFMA16(ahi, Blo, t2);
            t2 = MFMA16(alo, Bhi, t2);
#pragma unroll
            for (int r = 0; r < 4; ++r) acc[ntl][r] = fmaf(LO_INV, t2[r], acc[ntl][r]);
        }
    }

#pragma unroll
    for (int ntl = 0; ntl < NT_PER; ++ntl) {
        const int n = (nh * NT_PER + ntl) * 16 + l15;
#pragma unroll
        for (int r = 0; r < 4; ++r) {
            const int m = m0 + mt * 16 + l4 * 4 + r;
            Y[(size_t)m * NDIM + n] = acc[ntl][r];
        }
    }
}

// ---------------- top-5 per sim row (strict >, jax lower-index tie behavior) ------
__global__ __launch_bounds__(256)
void topk5(const float* __restrict__ sim, int* __restrict__ idx)
{
    const int row = blockIdx.x * 256 + threadIdx.x;
    const float* p = sim + (size_t)row * 256;
    float bv0 = -1e30f, bv1 = -1e30f, bv2 = -1e30f, bv3 = -1e30f, bv4 = -1e30f;
    int   bi0 = 0, bi1 = 0, bi2 = 0, bi3 = 0, bi4 = 0;
    for (int m4 = 0; m4 < 64; ++m4) {
        float4 v4 = *(const float4*)(p + m4 * 4);
        float vv[4] = {v4.x, v4.y, v4.z, v4.w};
#pragma unroll
        for (int c = 0; c < 4; ++c) {
            float v = vv[c];
            int   m = m4 * 4 + c;
            if (v > bv0) {
                if (v > bv1) {
                    bv0 = bv1; bi0 = bi1;
                    if (v > bv2) {
                        bv1 = bv2; bi1 = bi2;
                        if (v > bv3) {
                            bv2 = bv3; bi2 = bi3;
                            if (v > bv4) { bv3 = bv4; bi3 = bi4; bv4 = v; bi4 = m; }
                            else         { bv3 = v;  bi3 = m; }
                        } else { bv2 = v; bi2 = m; }
                    } else { bv1 = v; bi1 = m; }
                } else { bv0 = v; bi0 = m; }
            }
        }
    }
    int* o = idx + (size_t)row * 5;
    o[0] = bi0; o[1] = bi1; o[2] = bi2; o[3] = bi3; o[4] = bi4;
}

// ---------------- sparse GCN aggregation: out[n] = c*(X[n] + sum_j X[idx_j]) ------
template<bool RELU, int DIM>
__global__ __launch_bounds__(128)
void gcn_agg(const float* __restrict__ X, const int* __restrict__ idxs,
             float* __restrict__ outp, float cnorm)
{
    const int row = blockIdx.x;
    const int bbase = row & ~255;
    const int* id = idxs + (size_t)row * 5;
    const int i0 = bbase + id[0];
    const int i1 = bbase + id[1];
    const int i2 = bbase + id[2];
    const int i3 = bbase + id[3];
    const int i4 = bbase + id[4];
    const int t = threadIdx.x;
    if (DIM == 512) {
        const float4* Xp = (const float4*)X;
        float4 a = Xp[(size_t)row * 128 + t];
        float4 v;
        v = Xp[(size_t)i0 * 128 + t]; a.x += v.x; a.y += v.y; a.z += v.z; a.w += v.w;
        v = Xp[(size_t)i1 * 128 + t]; a.x += v.x; a.y += v.y; a.z += v.z; a.w += v.w;
        v = Xp[(size_t)i2 * 128 + t]; a.x += v.x; a.y += v.y; a.z += v.z; a.w += v.w;
        v = Xp[(size_t)i3 * 128 + t]; a.x += v.x; a.y += v.y; a.z += v.z; a.w += v.w;
        v = Xp[(size_t)i4 * 128 + t]; a.x += v.x; a.y += v.y; a.z += v.z; a.w += v.w;
        a.x *= cnorm; a.y *= cnorm; a.z *= cnorm; a.w *= cnorm;
        if (RELU) {
            a.x = fmaxf(a.x, 0.f); a.y = fmaxf(a.y, 0.f);
            a.z = fmaxf(a.z, 0.f); a.w = fmaxf(a.w, 0.f);
        }
        ((float4*)outp)[(size_t)row * 128 + t] = a;
    } else {
        float a = X[(size_t)row * 128 + t];
        a += X[(size_t)i0 * 128 + t];
        a += X[(size_t)i1 * 128 + t];
        a += X[(size_t)i2 * 128 + t];
        a += X[(size_t)i3 * 128 + t];
        a += X[(size_t)i4 * 128 + t];
        a *= cnorm;
        if (RELU) a = fmaxf(a, 0.f);
        outp[(size_t)row * 128 + t] = a;
    }
}

// ------------------------------- launcher -----------------------------------------
extern "C" void kernel_launch(void* const* d_in, const int* in_sizes, int n_in,
                              void* d_out, int out_size, void* d_ws, size_t ws_size,
                              hipStream_t stream)
{
    (void)in_sizes; (void)n_in; (void)out_size; (void)ws_size;

    const float* C_masked = (const float*)d_in[0];
    const float* W_proj   = (const float*)d_in[1];
    const float* b_proj   = (const float*)d_in[2];
    const float* Wih_f    = (const float*)d_in[3];
    const float* Whh_f    = (const float*)d_in[4];
    const float* bih_f    = (const float*)d_in[5];
    const float* bhh_f    = (const float*)d_in[6];
    const float* Wih_b    = (const float*)d_in[7];
    const float* Whh_b    = (const float*)d_in[8];
    const float* bih_b    = (const float*)d_in[9];
    const float* bhh_b    = (const float*)d_in[10];
    const float* W_gcn1   = (const float*)d_in[11];
    const float* W_gcn2   = (const float*)d_in[12];
    float* out = (float*)d_out;

    char* ws = (char*)d_ws;
    size_t o = 0;
    auto take = [&](size_t bytes) {
        size_t r = o;
        o = (o + bytes + 255) & ~(size_t)255;
        return r;
    };
    const size_t WCOMB_B = (size_t)768 * 256 * 4;
    const size_t PACK_B  = (size_t)48 * 8 * 2 * 512 * 2;   // 786432
    const size_t PACKG_B = (size_t)262144;
    const size_t o_wcf  = take(WCOMB_B);
    const size_t o_wcb  = take(WCOMB_B);
    const size_t o_bcf  = take(768 * 4);
    const size_t o_bcb  = take(768 * 4);
    const size_t o_rinv = take((size_t)65536 * 4);
    const size_t o_topk = take((size_t)65536 * 5 * 4);
    const size_t o_pwf  = take(PACK_B);
    const size_t o_pwb  = take(PACK_B);
    const size_t o_pg1  = take(PACKG_B);
    const size_t o_pg2  = take(PACKG_B);
    const size_t o_hst  = take((size_t)512 * 256 * 4);     // h checkpoint (512 KB)
    const size_t regionA = o;

    // chunked gi: 256 batches x 128 steps x 768 = 100.7 MB per direction
    const size_t GIC_BYTES = (size_t)256 * 128 * 768 * 4;
    const size_t H_BYTES   = (size_t)65536 * 512 * 4;      // 134.2 MB
    // peak: regionA + 2*GIC + H  ~= 342 MB (== R4's proven footprint)

    float* wcomb_f = (float*)(ws + o_wcf);
    float* wcomb_b = (float*)(ws + o_wcb);
    float* bcomb_f = (float*)(ws + o_bcf);
    float* bcomb_b = (float*)(ws + o_bcb);
    float* rinv    = (float*)(ws + o_rinv);
    int*   topk    = (int*)(ws + o_topk);
    unsigned short* packWf = (unsigned short*)(ws + o_pwf);
    unsigned short* packWb = (unsigned short*)(ws + o_pwb);
    unsigned short* packG1 = (unsigned short*)(ws + o_pg1);
    unsigned short* packG2 = (unsigned short*)(ws + o_pg2);
    float* hstate = (float*)(ws + o_hst);

    float* gi_fc = (float*)(ws + regionA);
    float* gi_bc = (float*)(ws + regionA + GIC_BYTES);
    float* Hbuf  = (float*)(ws + regionA + 2 * GIC_BYTES);

    // post-scan reuse of the gi-chunk region (2*GIC = 201.3 MB available)
    float* sim  = (float*)(ws + regionA);               // 67.1 MB
    float* XW1  = (float*)(ws + regionA + 67108864);    // 33.6 MB
    float* Z1   = (float*)(ws + regionA + 100663296);   // 33.6 MB
    float* Z1W2 = (float*)(ws + regionA);               // 134.2 MB (sim+XW1 dead)

    const dim3 blk(256);

    // 1. combined weights + biases; packs
    gemm_f32<false><<<dim3(2, 6, 1), blk, 0, stream>>>(
        768, 256, 512, Wih_f, 0, W_proj, 0, wcomb_f, 0, nullptr, nullptr, nullptr);
    gemm_f32<false><<<dim3(2, 6, 1), blk, 0, stream>>>(
        768, 256, 512, Wih_b, 0, W_proj, 0, wcomb_b, 0, nullptr, nullptr, nullptr);
    bias_combine<<<3, 256, 0, stream>>>(Wih_f, b_proj, bih_f, bcomb_f);
    bias_combine<<<3, 256, 0, stream>>>(Wih_b, b_proj, bih_b, bcomb_b);
    pack_w<<<768, 256, 0, stream>>>(wcomb_f, packWf);
    pack_w<<<768, 256, 0, stream>>>(wcomb_b, packWb);
    pack_bk<<<256, 256, 0, stream>>>(W_gcn1, packG1, 512, 128);
    pack_bk<<<256, 256, 0, stream>>>(W_gcn2, packG2, 128, 512);

    // 2. time-chunked gi + bidirectional parallel scan (2 phases x 128 steps)
    // phase 0: fwd consumes t in [0,128), bwd consumes t in [128,256)
    gi_gemm_c<<<512, 512, 0, stream>>>(C_masked, packWf, bcomb_f, gi_fc, 0);
    gi_gemm_c<<<512, 512, 0, stream>>>(C_masked, packWb, bcomb_b, gi_bc, 128);
    gru_scan_v8<<<128, 1024, 0, stream>>>(gi_fc, gi_bc, Whh_f, Whh_b,
                                          bhh_f, bhh_b, Hbuf, hstate, 0);
    // phase 1: fwd consumes [128,256), bwd consumes [0,128)
    gi_gemm_c<<<512, 512, 0, stream>>>(C_masked, packWf, bcomb_f, gi_fc, 128);
    gi_gemm_c<<<512, 512, 0, stream>>>(C_masked, packWb, bcomb_b, gi_bc, 0);
    gru_scan_v8<<<128, 1024, 0, stream>>>(gi_fc, gi_bc, Whh_f, Whh_b,
                                          bhh_f, bhh_b, Hbuf, hstate, 1);

    // 3. cosine-sim (MFMA, rinv folded) -> top-5
    rownorm<<<16384, blk, 0, stream>>>(Hbuf, rinv);
    sim_mfma<<<256, 512, 0, stream>>>(Hbuf, rinv, sim);
    topk5<<<256, blk, 0, stream>>>(sim, topk);

    // 4. GCN with A_norm = A / (6 + 1e-8)  (row-sum of A is always K+1 = 6)
    const float cnorm = (float)(1.0 / (6.0 + 1e-8));
    gcn_mm<512, 128, 4><<<1024, 512, 0, stream>>>(Hbuf, packG1, XW1);
    gcn_agg<true, 128><<<65536, 128, 0, stream>>>(XW1, topk, Z1, cnorm);
    gcn_mm<128, 512, 16><<<1024, 512, 0, stream>>>(Z1, packG2, Z1W2);
    gcn_agg<false, 512><<<65536, 128, 0, stream>>>(Z1W2, topk, out, cnorm);
}